// Round 1
// baseline (483.911 us; speedup 1.0000x reference)
//
#include <hip/hip_runtime.h>

#define NQ 10000
#define BS 2
#define NV 19560
#define NH 8
#define HD 32
#define EMB 256

// ---------------------------------------------------------------------------
// Tiled fp32 GEMM: C[M,N] = A[M,K] (+A2[M,K]) @ B[K,N] + bias[N]
// BM=64, BN=64, BK=16, 256 threads, 4x4 micro-tile.
// ---------------------------------------------------------------------------
template<bool ADD2>
__global__ __launch_bounds__(256) void sgemm_kernel(
    const float* __restrict__ A, const float* __restrict__ A2,
    const float* __restrict__ B, const float* __restrict__ bias,
    float* __restrict__ C, int M, int N, int K)
{
    constexpr int BM = 64, BN = 64, BK = 16;
    __shared__ float As[BK][BM];
    __shared__ float Bs[BK][BN];

    const int tid = threadIdx.x;
    const int tx = tid & 15;        // 0..15 -> N micro
    const int ty = tid >> 4;        // 0..15 -> M micro

    const int a_row = tid >> 2;         // 0..63
    const int a_col = (tid & 3) * 4;    // 0,4,8,12
    const int b_row = tid >> 4;         // 0..15
    const int b_col = (tid & 15) * 4;   // 0..60

    const int gRowA = blockIdx.x * BM + a_row;
    const int gColB = blockIdx.y * BN + b_col;

    float acc[4][4] = {};

    for (int k0 = 0; k0 < K; k0 += BK) {
        float4 av = make_float4(0.f, 0.f, 0.f, 0.f);
        if (gRowA < M) {
            av = *(const float4*)(A + (size_t)gRowA * K + k0 + a_col);
            if (ADD2) {
                float4 a2 = *(const float4*)(A2 + (size_t)gRowA * K + k0 + a_col);
                av.x += a2.x; av.y += a2.y; av.z += a2.z; av.w += a2.w;
            }
        }
        As[a_col + 0][a_row] = av.x;
        As[a_col + 1][a_row] = av.y;
        As[a_col + 2][a_row] = av.z;
        As[a_col + 3][a_row] = av.w;

        float4 bv = *(const float4*)(B + (size_t)(k0 + b_row) * N + gColB);
        *(float4*)&Bs[b_row][b_col] = bv;

        __syncthreads();

        #pragma unroll
        for (int kk = 0; kk < BK; kk++) {
            float4 a = *(const float4*)&As[kk][ty * 4];
            float4 b = *(const float4*)&Bs[kk][tx * 4];
            float ar[4] = {a.x, a.y, a.z, a.w};
            float br[4] = {b.x, b.y, b.z, b.w};
            #pragma unroll
            for (int i = 0; i < 4; i++)
                #pragma unroll
                for (int j = 0; j < 4; j++)
                    acc[i][j] += ar[i] * br[j];
        }
        __syncthreads();
    }

    const int gn = blockIdx.y * BN + tx * 4;
    float4 bb = *(const float4*)&bias[gn];
    #pragma unroll
    for (int i = 0; i < 4; i++) {
        int gm = blockIdx.x * BM + ty * 4 + i;
        if (gm < M) {
            float4 o;
            o.x = acc[i][0] + bb.x;
            o.y = acc[i][1] + bb.y;
            o.z = acc[i][2] + bb.z;
            o.w = acc[i][3] + bb.w;
            *(float4*)(C + (size_t)gm * N + gn) = o;
        }
    }
}

// ---------------------------------------------------------------------------
// Per-(b,q,h): softmax over 16 attn logits (in place) and convert offsets to
// pixel-space sampling coords (in place in the off buffer).
// pixel x = ref_x*W + off_x - 0.5 ; pixel y = ref_y*H + off_y - 0.5
// off layout per (b,q): [h][l][p][2] = 256 floats. attn: [h][l*4+p] = 128.
// reference_points: (bs, nq, 4, 2), z index == p (since P//Z == 1).
// ---------------------------------------------------------------------------
__global__ __launch_bounds__(256) void softmax_loc_kernel(
    float* __restrict__ attn, float* __restrict__ off,
    const float* __restrict__ refp)
{
    int idx = blockIdx.x * 256 + threadIdx.x;   // < BS*NQ*NH = 160000
    if (idx >= BS * NQ * NH) return;
    int h  = idx & 7;
    int bq = idx >> 3;

    float* ap = attn + (size_t)bq * 128 + h * 16;
    float lg[16];
    float mx = -1e30f;
    #pragma unroll
    for (int i = 0; i < 16; i++) { lg[i] = ap[i]; mx = fmaxf(mx, lg[i]); }
    float s = 0.f;
    #pragma unroll
    for (int i = 0; i < 16; i++) { lg[i] = __expf(lg[i] - mx); s += lg[i]; }
    float inv = 1.f / s;
    #pragma unroll
    for (int i = 0; i < 16; i++) ap[i] = lg[i] * inv;

    float* op = off + (size_t)bq * 256 + h * 32;
    const float* rp = refp + (size_t)bq * 8;
    const float Wf[4] = {160.f, 80.f, 40.f, 20.f};
    const float Hf[4] = {92.f, 46.f, 23.f, 12.f};
    #pragma unroll
    for (int l = 0; l < 4; l++) {
        #pragma unroll
        for (int p = 0; p < 4; p++) {
            float ox = op[l * 8 + p * 2 + 0];
            float oy = op[l * 8 + p * 2 + 1];
            float rx = rp[p * 2 + 0];
            float ry = rp[p * 2 + 1];
            op[l * 8 + p * 2 + 0] = rx * Wf[l] + ox - 0.5f;
            op[l * 8 + p * 2 + 1] = ry * Hf[l] + oy - 0.5f;
        }
    }
}

// ---------------------------------------------------------------------------
// Bilinear sampling + attention-weighted sum.
// 32 lanes per (b,q,h) group; lane = channel d. 8 groups per 256-thread block.
// v: (bs, nv, 8, 32) fp32 ; locs: (bs,nq,8,4,4,2) pixel coords ;
// attn: (bs,nq,8,16) softmaxed ; out: (bs,nq,256)
// ---------------------------------------------------------------------------
__global__ __launch_bounds__(256) void sample_kernel(
    const float* __restrict__ v, const float* __restrict__ locs,
    const float* __restrict__ attn, float* __restrict__ out)
{
    int gid = blockIdx.x * 8 + (threadIdx.x >> 5);  // (b*NQ+q)*8 + h
    int d = threadIdx.x & 31;
    int h = gid & 7;
    int bq = gid >> 3;
    int b = (bq >= NQ) ? 1 : 0;

    const float* lp = locs + (size_t)bq * 256 + h * 32;
    const float* ap = attn + (size_t)bq * 128 + h * 16;
    const int   Hs[4] = {92, 46, 23, 12};
    const int   Ws[4] = {160, 80, 40, 20};
    const int   st[4] = {0, 14720, 18400, 19320};

    const float* vb = v + ((size_t)b * NV) * 256 + h * 32 + d;

    float acc = 0.f;
    #pragma unroll
    for (int l = 0; l < 4; l++) {
        const int H = Hs[l], W = Ws[l];
        const float* vl = vb + (size_t)st[l] * 256;
        #pragma unroll
        for (int p = 0; p < 4; p++) {
            float x = lp[l * 8 + p * 2 + 0];
            float y = lp[l * 8 + p * 2 + 1];
            float w = ap[l * 4 + p];
            float x0f = floorf(x), y0f = floorf(y);
            float wx1 = x - x0f, wy1 = y - y0f;
            float wx0 = 1.f - wx1, wy0 = 1.f - wy1;
            int x0 = (int)x0f, y0 = (int)y0f;
            int x1 = x0 + 1, y1 = y0 + 1;
            bool vx0 = (unsigned)x0 < (unsigned)W;
            bool vx1 = (unsigned)x1 < (unsigned)W;
            bool vy0 = (unsigned)y0 < (unsigned)H;
            bool vy1 = (unsigned)y1 < (unsigned)H;
            float v00 = 0.f, v01 = 0.f, v10 = 0.f, v11 = 0.f;
            if (vy0 && vx0) v00 = vl[(size_t)(y0 * W + x0) * 256];
            if (vy0 && vx1) v01 = vl[(size_t)(y0 * W + x1) * 256];
            if (vy1 && vx0) v10 = vl[(size_t)(y1 * W + x0) * 256];
            if (vy1 && vx1) v11 = vl[(size_t)(y1 * W + x1) * 256];
            float s = v00 * (wy0 * wx0) + v01 * (wy0 * wx1)
                    + v10 * (wy1 * wx0) + v11 * (wy1 * wx1);
            acc += w * s;
        }
    }
    out[(size_t)bq * 256 + h * 32 + d] = acc;
}

extern "C" void kernel_launch(void* const* d_in, const int* in_sizes, int n_in,
                              void* d_out, int out_size, void* d_ws, size_t ws_size,
                              hipStream_t stream) {
    const float* query     = (const float*)d_in[0];
    const float* value     = (const float*)d_in[1];
    const float* query_pos = (const float*)d_in[2];
    const float* refp      = (const float*)d_in[3];
    const float* W_val     = (const float*)d_in[4];
    const float* b_val     = (const float*)d_in[5];
    const float* W_off     = (const float*)d_in[6];
    const float* b_off     = (const float*)d_in[7];
    const float* W_attn    = (const float*)d_in[8];
    const float* b_attn    = (const float*)d_in[9];
    float* out = (float*)d_out;

    float* ws    = (float*)d_ws;
    float* vproj = ws;                                   // 39120*256
    float* off   = vproj + (size_t)BS * NV * EMB;        // 20000*256
    float* attn  = off + (size_t)BS * NQ * EMB;          // 20000*128

    const int Mv = BS * NV;   // 39120
    const int Mq = BS * NQ;   // 20000

    // value projection
    dim3 g1((Mv + 63) / 64, EMB / 64);
    sgemm_kernel<false><<<g1, 256, 0, stream>>>(value, nullptr, W_val, b_val,
                                                vproj, Mv, EMB, EMB);
    // sampling offsets (q = query + query_pos fused into A load)
    dim3 g2((Mq + 63) / 64, EMB / 64);
    sgemm_kernel<true><<<g2, 256, 0, stream>>>(query, query_pos, W_off, b_off,
                                               off, Mq, EMB, EMB);
    // attention logits
    dim3 g3((Mq + 63) / 64, 128 / 64);
    sgemm_kernel<true><<<g3, 256, 0, stream>>>(query, query_pos, W_attn, b_attn,
                                               attn, Mq, 128, EMB);
    // softmax + pixel-space locations (in place)
    softmax_loc_kernel<<<(BS * NQ * NH + 255) / 256, 256, 0, stream>>>(attn, off, refp);
    // bilinear sample + weighted sum
    sample_kernel<<<BS * NQ * NH / 8, 256, 0, stream>>>(vproj, off, attn, out);
}

// Round 2
// 428.646 us; speedup vs baseline: 1.1289x; 1.1289x over previous
//
#include <hip/hip_runtime.h>

#define NQ 10000
#define BS 2
#define NV 19560
#define NH 8
#define HD 32
#define EMB 256

typedef __attribute__((ext_vector_type(8))) short bf16x8;
typedef __attribute__((ext_vector_type(4))) float f32x4;
typedef __attribute__((ext_vector_type(4))) short s16x4;

__device__ __forceinline__ unsigned short f2bf(float x) {
    unsigned u = __float_as_uint(x);
    u += 0x7FFFu + ((u >> 16) & 1u);       // round-to-nearest-even
    return (unsigned short)(u >> 16);
}
__device__ __forceinline__ float bf2f(unsigned short h) {
    return __uint_as_float(((unsigned)h) << 16);
}

// ---------------------------------------------------------------------------
// MFMA bf16 split-precision GEMM: C = (A [+A2]) @ B + bias, fp32 in/out.
// A (M x 256). B is [B0 | B1] column-concatenated: B0 (256 x N0), B1 (256 x N1).
// Output C0 (M x N0) and C1 (M x N1), row-major. 128x128 tile, BK=32,
// 256 threads = 4 waves in 2x2 of 64x64; each wave 4x4 grid of 16x16x32 MFMAs.
// Split trick: A = Ah + Al (bf16 each), B = Bh + Bl; D += AhBh + AhBl + AlBh
// -> ~2^-17 relative error, fp32-equivalent for this tolerance.
// Fragment layouts (m89/m120-verified): A[m=lane&15][k=(lane>>4)*8+j],
// B[n=lane&15][k=(lane>>4)*8+j] (stored transposed in LDS),
// C/D: col=lane&15, row=(lane>>4)*4+reg.
// ---------------------------------------------------------------------------
template<bool ADD2>
__global__ __launch_bounds__(256) void mfma_gemm(
    const float* __restrict__ A, const float* __restrict__ A2,
    const float* __restrict__ B0, const float* __restrict__ B1,
    const float* __restrict__ bias0, const float* __restrict__ bias1,
    float* __restrict__ C0, float* __restrict__ C1,
    int M, int N0, int N1)
{
    constexpr int LDW = 40;  // pad 32->40 shorts: rows 80B (16B-aligned), ~2-way bank alias
    __shared__ short Ah[128][LDW], Al[128][LDW], Bh[128][LDW], Bl[128][LDW];

    const int tid = threadIdx.x;
    const int nbase = blockIdx.y * 128;
    const bool second = (nbase >= N0);
    const float* __restrict__ Bsrc = second ? B1 : B0;
    const float* __restrict__ biasp = second ? bias1 : bias0;
    float* __restrict__ Cdst = second ? C1 : C0;
    const int ldb = second ? N1 : N0;
    const int col0 = second ? (nbase - N0) : nbase;

    const int m0 = blockIdx.x * 128;

    // A staging coords: thread t covers row t>>1, 16 consecutive k (half row)
    const int ar = tid >> 1;
    const int ac = (tid & 1) * 16;
    const int grow = m0 + ar;
    const bool aval = (grow < M);

    const int lane = tid & 63;
    const int wave = tid >> 6;
    const int wrow = (wave >> 1) * 64;
    const int wcol = (wave & 1) * 64;
    const int lr = lane & 15;
    const int lk = (lane >> 4) * 8;

    f32x4 acc[4][4] = {};

    for (int k0 = 0; k0 < EMB; k0 += 32) {
        // ---- stage A tile (128 x 32 fp32 -> hi/lo bf16 in LDS) ----
        #pragma unroll
        for (int g = 0; g < 4; g++) {
            f32x4 v = {};
            if (aval) {
                v = *(const f32x4*)(A + (size_t)grow * EMB + k0 + ac + g * 4);
                if (ADD2) {
                    f32x4 v2 = *(const f32x4*)(A2 + (size_t)grow * EMB + k0 + ac + g * 4);
                    v += v2;
                }
            }
            s16x4 h, l;
            #pragma unroll
            for (int e = 0; e < 4; e++) {
                float x = v[e];
                unsigned short hh = f2bf(x);
                h[e] = (short)hh;
                l[e] = (short)f2bf(x - bf2f(hh));
            }
            *(s16x4*)&Ah[ar][ac + g * 4] = h;
            *(s16x4*)&Al[ar][ac + g * 4] = l;
        }
        // ---- stage B tile (32 x 128 fp32, transposed to [n][k] hi/lo) ----
        #pragma unroll
        for (int j = 0; j < 4; j++) {
            int g = tid + 256 * j;
            int n = g & 127;
            int kq = g >> 7;            // 0..7
            int kk = k0 + kq * 4;
            s16x4 h, l;
            #pragma unroll
            for (int e = 0; e < 4; e++) {
                float x = Bsrc[(size_t)(kk + e) * ldb + col0 + n];
                unsigned short hh = f2bf(x);
                h[e] = (short)hh;
                l[e] = (short)f2bf(x - bf2f(hh));
            }
            *(s16x4*)&Bh[n][kq * 4] = h;
            *(s16x4*)&Bl[n][kq * 4] = l;
        }
        __syncthreads();

        bf16x8 ah[4], al[4], bh[4], bl[4];
        #pragma unroll
        for (int i = 0; i < 4; i++) {
            ah[i] = *(const bf16x8*)&Ah[wrow + i * 16 + lr][lk];
            al[i] = *(const bf16x8*)&Al[wrow + i * 16 + lr][lk];
        }
        #pragma unroll
        for (int j = 0; j < 4; j++) {
            bh[j] = *(const bf16x8*)&Bh[wcol + j * 16 + lr][lk];
            bl[j] = *(const bf16x8*)&Bl[wcol + j * 16 + lr][lk];
        }
        #pragma unroll
        for (int i = 0; i < 4; i++)
            #pragma unroll
            for (int j = 0; j < 4; j++) {
                acc[i][j] = __builtin_amdgcn_mfma_f32_16x16x32_bf16(ah[i], bh[j], acc[i][j], 0, 0, 0);
                acc[i][j] = __builtin_amdgcn_mfma_f32_16x16x32_bf16(ah[i], bl[j], acc[i][j], 0, 0, 0);
                acc[i][j] = __builtin_amdgcn_mfma_f32_16x16x32_bf16(al[i], bh[j], acc[i][j], 0, 0, 0);
            }
        __syncthreads();
    }

    // ---- epilogue: bias + store ----
    #pragma unroll
    for (int j = 0; j < 4; j++) {
        int cc = wcol + j * 16 + lr;
        float b = biasp[col0 + cc];
        #pragma unroll
        for (int i = 0; i < 4; i++) {
            int rbase = m0 + wrow + i * 16 + (lane >> 4) * 4;
            #pragma unroll
            for (int r = 0; r < 4; r++) {
                int gm = rbase + r;
                if (gm < M)
                    Cdst[(size_t)gm * ldb + col0 + cc] = acc[i][j][r] + b;
            }
        }
    }
}

// ---------------------------------------------------------------------------
// Per-(b,q,h): softmax over 16 attn logits (in place) and convert offsets to
// pixel-space sampling coords (in place). x = ref_x*W + off_x - 0.5.
// ---------------------------------------------------------------------------
__global__ __launch_bounds__(256) void softmax_loc_kernel(
    float* __restrict__ attn, float* __restrict__ off,
    const float* __restrict__ refp)
{
    int idx = blockIdx.x * 256 + threadIdx.x;
    if (idx >= BS * NQ * NH) return;
    int h  = idx & 7;
    int bq = idx >> 3;

    float* ap = attn + (size_t)bq * 128 + h * 16;
    float lg[16];
    float mx = -1e30f;
    #pragma unroll
    for (int i = 0; i < 16; i++) { lg[i] = ap[i]; mx = fmaxf(mx, lg[i]); }
    float s = 0.f;
    #pragma unroll
    for (int i = 0; i < 16; i++) { lg[i] = __expf(lg[i] - mx); s += lg[i]; }
    float inv = 1.f / s;
    #pragma unroll
    for (int i = 0; i < 16; i++) ap[i] = lg[i] * inv;

    float* op = off + (size_t)bq * 256 + h * 32;
    const float* rp = refp + (size_t)bq * 8;
    const float Wf[4] = {160.f, 80.f, 40.f, 20.f};
    const float Hf[4] = {92.f, 46.f, 23.f, 12.f};
    #pragma unroll
    for (int l = 0; l < 4; l++) {
        #pragma unroll
        for (int p = 0; p < 4; p++) {
            float ox = op[l * 8 + p * 2 + 0];
            float oy = op[l * 8 + p * 2 + 1];
            float rx = rp[p * 2 + 0];
            float ry = rp[p * 2 + 1];
            op[l * 8 + p * 2 + 0] = rx * Wf[l] + ox - 0.5f;
            op[l * 8 + p * 2 + 1] = ry * Hf[l] + oy - 0.5f;
        }
    }
}

// ---------------------------------------------------------------------------
// Bilinear sampling + attention-weighted sum. 32 lanes per (b,q,h), lane=chan.
// ---------------------------------------------------------------------------
__global__ __launch_bounds__(256) void sample_kernel(
    const float* __restrict__ v, const float* __restrict__ locs,
    const float* __restrict__ attn, float* __restrict__ out)
{
    int gid = blockIdx.x * 8 + (threadIdx.x >> 5);
    int d = threadIdx.x & 31;
    int h = gid & 7;
    int bq = gid >> 3;
    int b = (bq >= NQ) ? 1 : 0;

    const float* lp = locs + (size_t)bq * 256 + h * 32;
    const float* ap = attn + (size_t)bq * 128 + h * 16;
    const int   Hs[4] = {92, 46, 23, 12};
    const int   Ws[4] = {160, 80, 40, 20};
    const int   st[4] = {0, 14720, 18400, 19320};

    const float* vb = v + ((size_t)b * NV) * 256 + h * 32 + d;

    float acc = 0.f;
    #pragma unroll
    for (int l = 0; l < 4; l++) {
        const int H = Hs[l], W = Ws[l];
        const float* vl = vb + (size_t)st[l] * 256;
        #pragma unroll
        for (int p = 0; p < 4; p++) {
            float x = lp[l * 8 + p * 2 + 0];
            float y = lp[l * 8 + p * 2 + 1];
            float w = ap[l * 4 + p];
            float x0f = floorf(x), y0f = floorf(y);
            float wx1 = x - x0f, wy1 = y - y0f;
            float wx0 = 1.f - wx1, wy0 = 1.f - wy1;
            int x0 = (int)x0f, y0 = (int)y0f;
            int x1 = x0 + 1, y1 = y0 + 1;
            bool vx0 = (unsigned)x0 < (unsigned)W;
            bool vx1 = (unsigned)x1 < (unsigned)W;
            bool vy0 = (unsigned)y0 < (unsigned)H;
            bool vy1 = (unsigned)y1 < (unsigned)H;
            float v00 = 0.f, v01 = 0.f, v10 = 0.f, v11 = 0.f;
            if (vy0 && vx0) v00 = vl[(size_t)(y0 * W + x0) * 256];
            if (vy0 && vx1) v01 = vl[(size_t)(y0 * W + x1) * 256];
            if (vy1 && vx0) v10 = vl[(size_t)(y1 * W + x0) * 256];
            if (vy1 && vx1) v11 = vl[(size_t)(y1 * W + x1) * 256];
            float s = v00 * (wy0 * wx0) + v01 * (wy0 * wx1)
                    + v10 * (wy1 * wx0) + v11 * (wy1 * wx1);
            acc += w * s;
        }
    }
    out[(size_t)bq * 256 + h * 32 + d] = acc;
}

extern "C" void kernel_launch(void* const* d_in, const int* in_sizes, int n_in,
                              void* d_out, int out_size, void* d_ws, size_t ws_size,
                              hipStream_t stream) {
    const float* query     = (const float*)d_in[0];
    const float* value     = (const float*)d_in[1];
    const float* query_pos = (const float*)d_in[2];
    const float* refp      = (const float*)d_in[3];
    const float* W_val     = (const float*)d_in[4];
    const float* b_val     = (const float*)d_in[5];
    const float* W_off     = (const float*)d_in[6];
    const float* b_off     = (const float*)d_in[7];
    const float* W_attn    = (const float*)d_in[8];
    const float* b_attn    = (const float*)d_in[9];
    float* out = (float*)d_out;

    float* ws    = (float*)d_ws;
    float* vproj = ws;                                   // 39120*256
    float* off   = vproj + (size_t)BS * NV * EMB;        // 20000*256
    float* attn  = off + (size_t)BS * NQ * EMB;          // 20000*128

    const int Mv = BS * NV;   // 39120
    const int Mq = BS * NQ;   // 20000

    // value projection: C0 = value @ W_val + b_val
    dim3 gv((Mv + 127) / 128, 2);
    mfma_gemm<false><<<gv, 256, 0, stream>>>(value, nullptr, W_val, nullptr,
                                             b_val, nullptr, vproj, nullptr,
                                             Mv, 256, 0);
    // fused offsets+attn: [off | attn] = (query+query_pos) @ [W_off | W_attn]
    dim3 gq((Mq + 127) / 128, 3);
    mfma_gemm<true><<<gq, 256, 0, stream>>>(query, query_pos, W_off, W_attn,
                                            b_off, b_attn, off, attn,
                                            Mq, 256, 128);
    // softmax + pixel-space locations (in place)
    softmax_loc_kernel<<<(BS * NQ * NH + 255) / 256, 256, 0, stream>>>(attn, off, refp);
    // bilinear sample + weighted sum
    sample_kernel<<<BS * NQ * NH / 8, 256, 0, stream>>>(vproj, off, attn, out);
}

// Round 3
// 245.740 us; speedup vs baseline: 1.9692x; 1.7443x over previous
//
#include <hip/hip_runtime.h>

#define NQ 10000
#define BS 2
#define NV 19560
#define NH 8
#define HD 32
#define EMB 256

typedef __attribute__((ext_vector_type(8))) short bf16x8;
typedef __attribute__((ext_vector_type(4))) float f32x4;

__device__ __forceinline__ unsigned short f2bf(float x) {
    unsigned u = __float_as_uint(x);
    u += 0x7FFFu + ((u >> 16) & 1u);       // RNE
    return (unsigned short)(u >> 16);
}
__device__ __forceinline__ float bf2f(unsigned short h) {
    return __uint_as_float(((unsigned)h) << 16);
}

// ---------------------------------------------------------------------------
// Converters (memory-bound, hoisted out of GEMM main loops).
// ---------------------------------------------------------------------------
__global__ __launch_bounds__(256) void convert_val(const float* __restrict__ src,
                                                   ushort* __restrict__ dst) {
    size_t i = ((size_t)blockIdx.x * 256 + threadIdx.x) * 8;  // exact: M*256 % 8 == 0
    f32x4 a = *(const f32x4*)(src + i);
    f32x4 b = *(const f32x4*)(src + i + 4);
    ushort o[8];
    o[0]=f2bf(a.x); o[1]=f2bf(a.y); o[2]=f2bf(a.z); o[3]=f2bf(a.w);
    o[4]=f2bf(b.x); o[5]=f2bf(b.y); o[6]=f2bf(b.z); o[7]=f2bf(b.w);
    *(bf16x8*)(dst + i) = *(bf16x8*)o;
}

__global__ __launch_bounds__(256) void convert_q(const float* __restrict__ q,
                                                 const float* __restrict__ qp,
                                                 ushort* __restrict__ dst) {
    size_t i = ((size_t)blockIdx.x * 256 + threadIdx.x) * 8;
    f32x4 a = *(const f32x4*)(q + i)     + *(const f32x4*)(qp + i);
    f32x4 b = *(const f32x4*)(q + i + 4) + *(const f32x4*)(qp + i + 4);
    ushort o[8];
    o[0]=f2bf(a.x); o[1]=f2bf(a.y); o[2]=f2bf(a.z); o[3]=f2bf(a.w);
    o[4]=f2bf(b.x); o[5]=f2bf(b.y); o[6]=f2bf(b.z); o[7]=f2bf(b.w);
    *(bf16x8*)(dst + i) = *(bf16x8*)o;
}

// Transpose + hi/lo split all weight matrices into Bt[n][k] (n: 0-255 W_val,
// 256-511 W_off, 512-639 W_attn). Also concat biases. block = n, thread = k.
__global__ __launch_bounds__(256) void convert_W(
    const float* __restrict__ Wv, const float* __restrict__ Wo,
    const float* __restrict__ Wa, const float* __restrict__ bv,
    const float* __restrict__ bo, const float* __restrict__ ba,
    ushort* __restrict__ Bh, ushort* __restrict__ Bl, float* __restrict__ bias) {
    int n = blockIdx.x;      // 0..639
    int k = threadIdx.x;     // 0..255
    float x;
    if (n < 256)       x = Wv[k * 256 + n];
    else if (n < 512)  x = Wo[k * 256 + (n - 256)];
    else               x = Wa[k * 128 + (n - 512)];
    unsigned short h = f2bf(x);
    Bh[n * 256 + k] = h;
    Bl[n * 256 + k] = f2bf(x - bf2f(h));
    if (k == 0)
        bias[n] = (n < 256) ? bv[n] : (n < 512) ? bo[n - 256] : ba[n - 512];
}

// ---------------------------------------------------------------------------
// MFMA GEMM: C = A @ (Bh+Bl) + bias. A: M x 256 bf16. Bt: [n][k] bf16 hi/lo.
// 128x128 tile, BK=32, 4 waves 2x2. 2 MFMA per (i,j) per k-step.
// SPLITC=false: store bf16 planar (b,h,pix,d) value-proj; true: fp32 off|attn.
// ---------------------------------------------------------------------------
template<bool SPLITC>
__global__ __launch_bounds__(256) void mfma_gemm2(
    const ushort* __restrict__ A, const ushort* __restrict__ Bh_g,
    const ushort* __restrict__ Bl_g, const float* __restrict__ bias,
    ushort* __restrict__ Cv, float* __restrict__ C0, float* __restrict__ C1,
    int M)
{
    __shared__ short As[128][40], Bhs[128][40], Bls[128][40];  // pad 32->40

    const int tid = threadIdx.x;
    const int m0 = blockIdx.x * 128;
    const int n0 = blockIdx.y * 128;
    const int lane = tid & 63, wave = tid >> 6;
    const int wrow = (wave >> 1) * 64, wcol = (wave & 1) * 64;
    const int lr = lane & 15, quad = lane >> 4, lk = quad * 8;

    const int arow = tid >> 1;
    const int acol = (tid & 1) * 16;
    const bool aval = (m0 + arow) < M;
    const ushort* Ap  = A    + (size_t)(m0 + arow) * 256 + acol;
    const ushort* Bhp = Bh_g + (size_t)(n0 + arow) * 256 + acol;
    const ushort* Blp = Bl_g + (size_t)(n0 + arow) * 256 + acol;

    f32x4 acc[4][4] = {};

    for (int k0 = 0; k0 < 256; k0 += 32) {
        bf16x8 a0 = {}, a1 = {};
        if (aval) {
            a0 = *(const bf16x8*)(Ap + k0);
            a1 = *(const bf16x8*)(Ap + k0 + 8);
        }
        bf16x8 h0 = *(const bf16x8*)(Bhp + k0);
        bf16x8 h1 = *(const bf16x8*)(Bhp + k0 + 8);
        bf16x8 l0 = *(const bf16x8*)(Blp + k0);
        bf16x8 l1 = *(const bf16x8*)(Blp + k0 + 8);
        *(bf16x8*)&As[arow][acol]      = a0;
        *(bf16x8*)&As[arow][acol + 8]  = a1;
        *(bf16x8*)&Bhs[arow][acol]     = h0;
        *(bf16x8*)&Bhs[arow][acol + 8] = h1;
        *(bf16x8*)&Bls[arow][acol]     = l0;
        *(bf16x8*)&Bls[arow][acol + 8] = l1;
        __syncthreads();

        bf16x8 af[4], bhf[4], blf[4];
        #pragma unroll
        for (int i = 0; i < 4; i++)
            af[i] = *(const bf16x8*)&As[wrow + i * 16 + lr][lk];
        #pragma unroll
        for (int j = 0; j < 4; j++) {
            bhf[j] = *(const bf16x8*)&Bhs[wcol + j * 16 + lr][lk];
            blf[j] = *(const bf16x8*)&Bls[wcol + j * 16 + lr][lk];
        }
        #pragma unroll
        for (int i = 0; i < 4; i++)
            #pragma unroll
            for (int j = 0; j < 4; j++) {
                acc[i][j] = __builtin_amdgcn_mfma_f32_16x16x32_bf16(af[i], bhf[j], acc[i][j], 0, 0, 0);
                acc[i][j] = __builtin_amdgcn_mfma_f32_16x16x32_bf16(af[i], blf[j], acc[i][j], 0, 0, 0);
            }
        __syncthreads();
    }

    #pragma unroll
    for (int j = 0; j < 4; j++) {
        int cc = wcol + j * 16 + lr;
        int col = n0 + cc;
        float bb = bias[col];
        #pragma unroll
        for (int i = 0; i < 4; i++) {
            int gmb = m0 + wrow + i * 16 + quad * 4;
            #pragma unroll
            for (int r = 0; r < 4; r++) {
                int gm = gmb + r;
                if (gm < M) {
                    float val = acc[i][j][r] + bb;
                    if (!SPLITC) {
                        int h = col >> 5, d = col & 31;
                        int b = (gm >= NV) ? 1 : 0;
                        int pix = gm - b * NV;
                        Cv[((size_t)(b * 8 + h) * NV + pix) * 32 + d] = f2bf(val);
                    } else {
                        if (col < 256) C0[(size_t)gm * 256 + col] = val;
                        else           C1[(size_t)gm * 128 + (col - 256)] = val;
                    }
                }
            }
        }
    }
}

// ---------------------------------------------------------------------------
// Fused softmax + location + bilinear gather. Block = one (b,q), 256 threads.
// Phase 1 (t<128: one (h,l,p) point each): softmax over 16 logits via shuffle,
// pixel coords x=ref*W+off-0.5, clamped corner element-offsets + validity-
// premultiplied weights -> LDS. Phase 2: group of 32 lanes per head, lane=chan,
// branch-free 4-corner gathers from bf16 planar v.
// ---------------------------------------------------------------------------
__global__ __launch_bounds__(256) void sample2(
    const ushort* __restrict__ v, const float* __restrict__ off,
    const float* __restrict__ attn, const float* __restrict__ refp,
    float* __restrict__ out)
{
    __shared__ int   s_off[128][5];
    __shared__ float s_w[128][5];

    const int bq = blockIdx.x;
    const int b = (bq >= NQ) ? 1 : 0;
    const int t = threadIdx.x;

    if (t < 128) {
        const int h = t >> 4, i = t & 15, l = i >> 2, p = i & 3;
        // softmax over the 16 logits of this head (lanes grouped by 16)
        float logit = attn[(size_t)bq * 128 + t];
        float mx = logit;
        #pragma unroll
        for (int m = 1; m < 16; m <<= 1) mx = fmaxf(mx, __shfl_xor(mx, m, 16));
        float e = __expf(logit - mx);
        float s = e;
        #pragma unroll
        for (int m = 1; m < 16; m <<= 1) s += __shfl_xor(s, m, 16);
        float w = e / s;

        const float Wf[4] = {160.f, 80.f, 40.f, 20.f};
        const float Hf[4] = {92.f, 46.f, 23.f, 12.f};
        const int   Wi[4] = {160, 80, 40, 20};
        const int   Hi[4] = {92, 46, 23, 12};
        const int   st[4] = {0, 14720, 18400, 19320};

        float ox = off[(size_t)bq * 256 + h * 32 + l * 8 + p * 2];
        float oy = off[(size_t)bq * 256 + h * 32 + l * 8 + p * 2 + 1];
        float rx = refp[(size_t)bq * 8 + p * 2];
        float ry = refp[(size_t)bq * 8 + p * 2 + 1];
        float x = rx * Wf[l] + ox - 0.5f;
        float y = ry * Hf[l] + oy - 0.5f;
        float x0f = floorf(x), y0f = floorf(y);
        float wx1 = x - x0f, wy1 = y - y0f;
        float wx0 = 1.f - wx1, wy0 = 1.f - wy1;
        int x0 = (int)x0f, y0 = (int)y0f;
        const int W = Wi[l], H = Hi[l];
        float mx0 = ((unsigned)x0       < (unsigned)W) ? 1.f : 0.f;
        float mx1 = ((unsigned)(x0 + 1) < (unsigned)W) ? 1.f : 0.f;
        float my0 = ((unsigned)y0       < (unsigned)H) ? 1.f : 0.f;
        float my1 = ((unsigned)(y0 + 1) < (unsigned)H) ? 1.f : 0.f;
        int xc0 = min(max(x0, 0), W - 1);
        int xc1 = min(max(x0 + 1, 0), W - 1);
        int yc0 = min(max(y0, 0), H - 1);
        int yc1 = min(max(y0 + 1, 0), H - 1);
        int base = ((b * 8 + h) * NV + st[l]) * 32;
        s_off[t][0] = base + (yc0 * W + xc0) * 32;
        s_off[t][1] = base + (yc0 * W + xc1) * 32;
        s_off[t][2] = base + (yc1 * W + xc0) * 32;
        s_off[t][3] = base + (yc1 * W + xc1) * 32;
        s_w[t][0] = w * wy0 * wx0 * my0 * mx0;
        s_w[t][1] = w * wy0 * wx1 * my0 * mx1;
        s_w[t][2] = w * wy1 * wx0 * my1 * mx0;
        s_w[t][3] = w * wy1 * wx1 * my1 * mx1;
    }
    __syncthreads();

    const int h = t >> 5, d = t & 31;
    float acc = 0.f;
    #pragma unroll 4
    for (int i = 0; i < 16; i++) {
        int idx = h * 16 + i;
        int o0 = s_off[idx][0], o1 = s_off[idx][1];
        int o2 = s_off[idx][2], o3 = s_off[idx][3];
        float w0 = s_w[idx][0], w1 = s_w[idx][1];
        float w2 = s_w[idx][2], w3 = s_w[idx][3];
        acc += w0 * bf2f(v[o0 + d]) + w1 * bf2f(v[o1 + d])
             + w2 * bf2f(v[o2 + d]) + w3 * bf2f(v[o3 + d]);
    }
    out[(size_t)bq * 256 + t] = acc;
}

extern "C" void kernel_launch(void* const* d_in, const int* in_sizes, int n_in,
                              void* d_out, int out_size, void* d_ws, size_t ws_size,
                              hipStream_t stream) {
    const float* query     = (const float*)d_in[0];
    const float* value     = (const float*)d_in[1];
    const float* query_pos = (const float*)d_in[2];
    const float* refp      = (const float*)d_in[3];
    const float* W_val     = (const float*)d_in[4];
    const float* b_val     = (const float*)d_in[5];
    const float* W_off     = (const float*)d_in[6];
    const float* b_off     = (const float*)d_in[7];
    const float* W_attn    = (const float*)d_in[8];
    const float* b_attn    = (const float*)d_in[9];
    float* out = (float*)d_out;

    // Workspace layout (val_bf aliases off: val_bf dead before off is written)
    char* w = (char*)d_ws;
    float*  off     = (float*)w;
    ushort* val_bf  = (ushort*)w;            w += 20480000;  // max(off, val_bf)
    float*  attn    = (float*)w;             w += 10240000;
    ushort* qsum_bf = (ushort*)w;            w += 10240000;
    ushort* vp_bf   = (ushort*)w;            w += 20029440;  // planar (b,h,NV,32)
    ushort* Bt_hi   = (ushort*)w;            w += 327680;    // 640 x 256
    ushort* Bt_lo   = (ushort*)w;            w += 327680;
    float*  bias_c  = (float*)w;             w += 2560;

    const int Mv = BS * NV;   // 39120
    const int Mq = BS * NQ;   // 20000

    convert_val<<<4890, 256, 0, stream>>>(value, val_bf);            // 39120*256/8
    convert_q<<<2500, 256, 0, stream>>>(query, query_pos, qsum_bf);  // 20000*256/8
    convert_W<<<640, 256, 0, stream>>>(W_val, W_off, W_attn, b_val, b_off, b_attn,
                                       Bt_hi, Bt_lo, bias_c);

    dim3 gv((Mv + 127) / 128, 2);
    mfma_gemm2<false><<<gv, 256, 0, stream>>>(val_bf, Bt_hi, Bt_lo, bias_c,
                                              vp_bf, nullptr, nullptr, Mv);
    dim3 gq((Mq + 127) / 128, 3);
    mfma_gemm2<true><<<gq, 256, 0, stream>>>(qsum_bf, Bt_hi + 256 * 256,
                                             Bt_lo + 256 * 256, bias_c + 256,
                                             nullptr, off, attn, Mq);
    sample2<<<BS * NQ, 256, 0, stream>>>(vp_bf, off, attn, refp, out);
}